// Round 5
// baseline (250.848 us; speedup 1.0000x reference)
//
#include <hip/hip_runtime.h>
#include <math.h>

#define BB 4
#define LL 1024
#define DD 512
#define HH 8
#define DEP 64
#define NEGV (-1.0e9f)

typedef __attribute__((ext_vector_type(8))) short bf16x8;
typedef __attribute__((ext_vector_type(4))) float f32x4;
typedef unsigned short u16;
typedef unsigned int u32;

// ---- scalar slots in ws (float offsets) ----
#define S_GMAX 0
#define S_TMAX 1
#define S_TMIN 2
#define S_MUL  4     // 4
#define S_SUM  8     // 32
#define S_M    40    // 32
#define S_C    72    // 32
#define P_TMAX 128   // 256 partials (k_tminmax)
#define P_TMIN 384   // 256 partials
#define P_GMAX 640   // 2048 partials (k3: 16 qstripes x 32 bh x 4 kz)
#define SCAL_F 2816
#define PER_T  (BB*HH*LL*DEP)   // 2097152 bf16 elems per tensor

__device__ inline u16 f2b(float x) {
  u32 u = __float_as_uint(x);
  return (u16)((u + 0x7FFFu + ((u >> 16) & 1u)) >> 16);
}
__device__ inline float b2f(u16 h) { return __uint_as_float(((u32)h) << 16); }

__device__ inline void atomicMaxF(float* addr, float val) {
  unsigned int* ua = (unsigned int*)addr;
  unsigned int old = *ua;
  while (__uint_as_float(old) < val) {
    unsigned int assumed = old;
    old = atomicCAS(ua, assumed, __float_as_uint(val));
    if (old == assumed) break;
  }
}

// ---- K0: init accumulator scalars ----
__global__ void k0_init(float* ws) {
  int t = threadIdx.x;
  if (t < 4)  ws[S_MUL + t] = 0.0f;
  if (t < 32) { ws[S_SUM + t] = 0.0f; ws[S_M + t] = -INFINITY; ws[S_C + t] = 0.0f; }
}

// ---- count_nonzero(protok, axis=1) ----
__global__ void k_count(const float* __restrict__ protok, float* ws) {
  int b = blockIdx.x;
  int cnt = 0;
  for (int l = threadIdx.x; l < LL; l += blockDim.x)
    cnt += (protok[b*LL + l] != 0.0f) ? 1 : 0;
  __shared__ int sh[4];
  int lane = threadIdx.x & 63, w = threadIdx.x >> 6;
  #pragma unroll
  for (int o = 32; o > 0; o >>= 1) cnt += __shfl_down(cnt, o);
  if (lane == 0) sh[w] = cnt;
  __syncthreads();
  if (threadIdx.x == 0) ws[S_MUL + b] = (float)(sh[0] + sh[1] + sh[2] + sh[3]);
}

// ---- min/max over both statpot tensors: block partials, NO atomics ----
__global__ __launch_bounds__(256) void k_tminmax(const float* __restrict__ hb,
                                                 const float* __restrict__ pi,
                                                 float* __restrict__ ws) {
  const int g = blockIdx.x*256 + threadIdx.x;    // 65536 threads
  float mx = -INFINITY, mn = INFINITY;
  #pragma unroll
  for (int rep = 0; rep < 4; ++rep) {
    float4 a[4], c[4];
    #pragma unroll
    for (int j = 0; j < 4; ++j) {
      size_t idx = (size_t)rep*262144 + (size_t)j*65536 + g;
      a[j] = ((const float4*)hb)[idx];
      c[j] = ((const float4*)pi)[idx];
    }
    #pragma unroll
    for (int j = 0; j < 4; ++j) {
      mx = fmaxf(mx, fmaxf(fmaxf(a[j].x, a[j].y), fmaxf(a[j].z, a[j].w)));
      mx = fmaxf(mx, fmaxf(fmaxf(c[j].x, c[j].y), fmaxf(c[j].z, c[j].w)));
      mn = fminf(mn, fminf(fminf(a[j].x, a[j].y), fminf(a[j].z, a[j].w)));
      mn = fminf(mn, fminf(fminf(c[j].x, c[j].y), fminf(c[j].z, c[j].w)));
    }
  }
  __shared__ float shx[4], shn[4];
  int lane = threadIdx.x & 63, w = threadIdx.x >> 6;
  #pragma unroll
  for (int o = 32; o > 0; o >>= 1) {
    mx = fmaxf(mx, __shfl_down(mx, o));
    mn = fminf(mn, __shfl_down(mn, o));
  }
  if (lane == 0) { shx[w] = mx; shn[w] = mn; }
  __syncthreads();
  if (threadIdx.x == 0) {
    ws[P_TMAX + blockIdx.x] = fmaxf(fmaxf(shx[0], shx[1]), fmaxf(shx[2], shx[3]));
    ws[P_TMIN + blockIdx.x] = fminf(fminf(shn[0], shn[1]), fminf(shn[2], shn[3]));
  }
}

// ---- k_red1: fold tminmax partials ----
__global__ void k_red1(float* __restrict__ ws) {
  const int t = threadIdx.x;   // 256
  float tm = ws[P_TMAX + t];
  float tn = ws[P_TMIN + t];
  __shared__ float st[4], sn[4];
  int lane = t & 63, w = t >> 6;
  #pragma unroll
  for (int o = 32; o > 0; o >>= 1) {
    tm = fmaxf(tm, __shfl_down(tm, o));
    tn = fminf(tn, __shfl_down(tn, o));
  }
  if (lane == 0) { st[w] = tm; sn[w] = tn; }
  __syncthreads();
  if (t == 0) {
    ws[S_TMAX] = fmaxf(fmaxf(st[0], st[1]), fmaxf(st[2], st[3]));
    ws[S_TMIN] = fminf(fminf(sn[0], sn[1]), fminf(sn[2], sn[3]));
  }
}

// ---- k_red2: fold gmax partials (2048) ----
__global__ void k_red2(float* __restrict__ ws) {
  const int t = threadIdx.x;   // 256
  float gm = -INFINITY;
  #pragma unroll
  for (int j = 0; j < 8; ++j) gm = fmaxf(gm, ws[P_GMAX + j*256 + t]);
  __shared__ float sg[4];
  int lane = t & 63, w = t >> 6;
  #pragma unroll
  for (int o = 32; o > 0; o >>= 1) gm = fmaxf(gm, __shfl_down(gm, o));
  if (lane == 0) sg[w] = gm;
  __syncthreads();
  if (t == 0) ws[S_GMAX] = fmaxf(fmaxf(sg[0], sg[1]), fmaxf(sg[2], sg[3]));
}

// ---- k_taug: scaled+transposed bf16 table TG[b*2+tb][k][q] ----
__global__ __launch_bounds__(256) void k_taug(
    const float* __restrict__ hb, const float* __restrict__ pi,
    const float* __restrict__ w_aug, const float* __restrict__ wsf,
    u16* __restrict__ TG) {
  const int z = blockIdx.z;          // b*2 + tb
  const int b = z >> 1, tb = z & 1;
  const float wg = w_aug[0];
  const float tmaxr = wsf[S_TMAX], tminr = wsf[S_TMIN];
  const float tden = (wg >= 0.0f) ? (wg * tmaxr) : (wg * tminr);
  const float sc_ = wg / tden;
  const float* src = (tb ? pi : hb) + (size_t)b*LL*LL;
  const int k0 = blockIdx.x*64, q0 = blockIdx.y*64;
  __shared__ u16 Ls[64][72];
  const int t = threadIdx.x;
  {
    const int r = t>>2, c16 = (t&3)*16;   // q-local row r, k-local cols c16..
    float v[16];
    #pragma unroll
    for (int j=0;j<4;++j) {
      float4 f = *(const float4*)&src[(size_t)(q0+r)*LL + k0 + c16 + 4*j];
      v[4*j]=f.x*sc_; v[4*j+1]=f.y*sc_; v[4*j+2]=f.z*sc_; v[4*j+3]=f.w*sc_;
    }
    u32 pk_[8];
    #pragma unroll
    for (int j=0;j<8;++j) pk_[j] = (u32)f2b(v[2*j]) | ((u32)f2b(v[2*j+1])<<16);
    *(int4*)&Ls[r][c16]   = make_int4(pk_[0],pk_[1],pk_[2],pk_[3]);
    *(int4*)&Ls[r][c16+8] = make_int4(pk_[4],pk_[5],pk_[6],pk_[7]);
  }
  __syncthreads();
  {
    const int kk = t>>2, qc = (t&3)*16;   // output row k0+kk, q cols q0+qc..
    u16 u[16];
    #pragma unroll
    for (int j=0;j<16;++j) u[j] = Ls[qc+j][kk];
    u32 q_[8];
    #pragma unroll
    for (int j=0;j<8;++j) q_[j] = (u32)u[2*j] | ((u32)u[2*j+1]<<16);
    size_t dst = ((size_t)z*LL + k0 + kk)*LL + q0 + qc;
    *(int4*)&TG[dst]   = make_int4(q_[0],q_[1],q_[2],q_[3]);
    *(int4*)&TG[dst+8] = make_int4(q_[4],q_[5],q_[6],q_[7]);
  }
}

// ---- k_xb: convert q and kv to bf16 once ----
__global__ __launch_bounds__(256) void k_xb(const float* __restrict__ q,
                                            const float* __restrict__ kv,
                                            u16* __restrict__ Xb) {
  int tg = blockIdx.x*256 + threadIdx.x;       // 524288 threads
  int which = tg >> 18;                        // 0: q, 1: kv
  size_t off8 = (size_t)(tg & 262143) * 8;
  const float* s = which ? kv : q;
  float4 f0 = *(const float4*)&s[off8];
  float4 f1 = *(const float4*)&s[off8 + 4];
  u32 p0 = (u32)f2b(f0.x) | ((u32)f2b(f0.y) << 16);
  u32 p1 = (u32)f2b(f0.z) | ((u32)f2b(f0.w) << 16);
  u32 p2 = (u32)f2b(f1.x) | ((u32)f2b(f1.y) << 16);
  u32 p3 = (u32)f2b(f1.z) | ((u32)f2b(f1.w) << 16);
  *(int4*)&Xb[(size_t)which*PER_T + off8] = make_int4(p0, p1, p2, p3);
}

// ---- k_wt: transpose+bf16 the 4 weight matrices -> WT[g][n][k] ----
__global__ __launch_bounds__(256) void k_wt(
    const float* __restrict__ wq, const float* __restrict__ wk,
    const float* __restrict__ wv, const float* __restrict__ wo,
    u16* __restrict__ WTb) {
  const int g = blockIdx.z;
  const float* W = (g==0)?wq:(g==1)?wk:(g==2)?wv:wo;
  const int k0 = blockIdx.x*64, n0 = blockIdx.y*64;
  __shared__ u16 Ls[64][72];
  const int t = threadIdx.x;
  {
    const int r = t>>2, c16 = (t&3)*16;
    float v[16];
    #pragma unroll
    for (int j=0;j<4;++j) {
      float4 f = *(const float4*)&W[(size_t)(k0+r)*DD + n0 + c16 + 4*j];
      v[4*j]=f.x; v[4*j+1]=f.y; v[4*j+2]=f.z; v[4*j+3]=f.w;
    }
    u32 pk_[8];
    #pragma unroll
    for (int j=0;j<8;++j) pk_[j] = (u32)f2b(v[2*j]) | ((u32)f2b(v[2*j+1])<<16);
    *(int4*)&Ls[r][c16]   = make_int4(pk_[0],pk_[1],pk_[2],pk_[3]);
    *(int4*)&Ls[r][c16+8] = make_int4(pk_[4],pk_[5],pk_[6],pk_[7]);
  }
  __syncthreads();
  {
    const int n = t>>2, kk = (t&3)*16;
    u16 u[16];
    #pragma unroll
    for (int j=0;j<16;++j) u[j] = Ls[kk+j][n];
    u32 q_[8];
    #pragma unroll
    for (int j=0;j<8;++j) q_[j] = (u32)u[2*j] | ((u32)u[2*j+1]<<16);
    size_t dst = ((size_t)(g*DD + n0 + n))*DD + k0 + kk;
    *(int4*)&WTb[dst]   = make_int4(q_[0],q_[1],q_[2],q_[3]);
    *(int4*)&WTb[dst+8] = make_int4(q_[4],q_[5],q_[6],q_[7]);
  }
}

// ---- K1: three input projections via MFMA; V is stored transposed ----
__global__ __launch_bounds__(256) void k1_proj(
    const float* __restrict__ protok,
    const float* __restrict__ bq, const float* __restrict__ bk,
    const float* __restrict__ bv,
    const u16* __restrict__ Xb, const u16* __restrict__ WTb,
    u16* __restrict__ QPb, u16* __restrict__ KHb, u16* __restrict__ VTb) {
  const int gid = blockIdx.z;
  const u16* X = Xb + (gid == 0 ? 0 : (size_t)PER_T);
  const float* bia = (gid == 0) ? bq : (gid == 1) ? bk : bv;
  const int m0 = blockIdx.x*64;
  const int h  = blockIdx.y;
  __shared__ u16 As[64][72];
  __shared__ u16 Bs[64][72];
  const int t = threadIdx.x;
  const int w = t>>6, lane = t&63, i = lane&15, g2 = lane>>4;
  const int sr = t>>2, sc = (t&3)*16;

  f32x4 acc[4];
  #pragma unroll
  for (int ct=0;ct<4;++ct) acc[ct] = (f32x4){0.f,0.f,0.f,0.f};

  for (int kk0 = 0; kk0 < DD; kk0 += 64) {
    __syncthreads();
    {
      size_t sx = (size_t)(m0+sr)*DD + kk0 + sc;
      *(int4*)&As[sr][sc]   = *(const int4*)&X[sx];
      *(int4*)&As[sr][sc+8] = *(const int4*)&X[sx+8];
    }
    {
      size_t src = ((size_t)(gid*DD + h*64 + sr))*DD + kk0 + sc;
      *(int4*)&Bs[sr][sc]   = *(const int4*)&WTb[src];
      *(int4*)&Bs[sr][sc+8] = *(const int4*)&WTb[src+8];
    }
    __syncthreads();
    bf16x8 a0 = *(const bf16x8*)&As[16*w + i][g2*8];
    bf16x8 a1 = *(const bf16x8*)&As[16*w + i][32 + g2*8];
    #pragma unroll
    for (int ct=0; ct<4; ++ct) {
      bf16x8 b0 = *(const bf16x8*)&Bs[ct*16 + i][g2*8];
      bf16x8 b1 = *(const bf16x8*)&Bs[ct*16 + i][32 + g2*8];
      acc[ct] = __builtin_amdgcn_mfma_f32_16x16x32_bf16(a0, b0, acc[ct], 0,0,0);
      acc[ct] = __builtin_amdgcn_mfma_f32_16x16x32_bf16(a1, b1, acc[ct], 0,0,0);
    }
  }
  __syncthreads();
  const int lrow = 16*w + g2*4;
  if (gid == 2) {
    #pragma unroll
    for (int ct=0;ct<4;++ct)
      #pragma unroll
      for (int r=0;r<4;++r)
        As[lrow + r][ct*16 + i] = f2b(acc[ct][r] + bia[h*64 + ct*16 + i]);
    __syncthreads();
    const int b = m0 >> 10, l0 = m0 & 1023;
    const int d = t>>2, lc = (t&3)*16;
    u16 u[16];
    #pragma unroll
    for (int j=0;j<16;++j) u[j] = As[lc+j][d];
    u32 q_[8];
    #pragma unroll
    for (int j=0;j<8;++j) q_[j] = (u32)u[2*j] | ((u32)u[2*j+1]<<16);
    size_t dst = ((size_t)(b*HH + h)*DEP + d)*LL + l0 + lc;
    *(int4*)&VTb[dst]   = make_int4(q_[0],q_[1],q_[2],q_[3]);
    *(int4*)&VTb[dst+8] = make_int4(q_[4],q_[5],q_[6],q_[7]);
  } else {
    u16* Y = (gid == 0) ? QPb : KHb;
    #pragma unroll
    for (int ct=0;ct<4;++ct)
      #pragma unroll
      for (int r=0;r<4;++r) {
        int m = m0 + lrow + r;
        float keep = (gid == 0) ? ((protok[m] != 0.0f) ? 1.0f : 0.0f) : 1.0f;
        int b = m >> 10, l = m & 1023;
        float val = (acc[ct][r] + bia[h*64 + ct*16 + i]) * keep;
        Y[((size_t)(b*HH + h)*LL + l)*DEP + ct*16 + i] = f2b(val);
      }
  }
}

// ---- K3: partial max of raw QK^T; 4 K-tiles per block ----
__global__ __launch_bounds__(256) void k3_gmax(
    const u16* __restrict__ QPb, const u16* __restrict__ KHb,
    float* __restrict__ wsf) {
  const int q0 = blockIdx.x*64, bh = blockIdx.y, kz = blockIdx.z;
  __shared__ u16 Qs[64][72];
  __shared__ u16 Ks[2][64][72];
  const int t = threadIdx.x;
  const int w = t>>6, lane = t&63, i = lane&15, g2 = lane>>4;
  const int sr = t>>2, sc = (t&3)*16;
  const u16* Qb = QPb + (size_t)bh*LL*DEP;
  const u16* Kb = KHb + (size_t)bh*LL*DEP;
  {
    size_t sq = (size_t)(q0 + sr)*DEP + sc;
    *(int4*)&Qs[sr][sc]   = *(const int4*)&Qb[sq];
    *(int4*)&Qs[sr][sc+8] = *(const int4*)&Qb[sq+8];
  }
  const int kb = kz*4;  // first K-tile index
  int4 rn0 = *(const int4*)&Kb[(size_t)(kb*64 + sr)*DEP + sc];
  int4 rn1 = *(const int4*)&Kb[(size_t)(kb*64 + sr)*DEP + sc + 8];
  __syncthreads();
  *(int4*)&Ks[0][sr][sc]   = rn0;
  *(int4*)&Ks[0][sr][sc+8] = rn1;
  rn0 = *(const int4*)&Kb[(size_t)((kb+1)*64 + sr)*DEP + sc];
  rn1 = *(const int4*)&Kb[(size_t)((kb+1)*64 + sr)*DEP + sc + 8];
  __syncthreads();
  bf16x8 a0 = *(const bf16x8*)&Qs[16*w + i][g2*8];
  bf16x8 a1 = *(const bf16x8*)&Qs[16*w + i][32 + g2*8];
  float mx = -INFINITY;
  for (int kt = 0; kt < 4; ++kt) {
    const int cur = kt & 1;
    #pragma unroll
    for (int ct=0;ct<4;++ct) {
      bf16x8 b0 = *(const bf16x8*)&Ks[cur][ct*16 + i][g2*8];
      bf16x8 b1 = *(const bf16x8*)&Ks[cur][ct*16 + i][32 + g2*8];
      f32x4 z = (f32x4){0.f,0.f,0.f,0.f};
      z = __builtin_amdgcn_mfma_f32_16x16x32_bf16(a0, b0, z, 0,0,0);
      z = __builtin_amdgcn_mfma_f32_16x16x32_bf16(a1, b1, z, 0,0,0);
      mx = fmaxf(mx, fmaxf(fmaxf(z[0],z[1]), fmaxf(z[2],z[3])));
    }
    if (kt < 3) {
      __syncthreads();
      *(int4*)&Ks[cur^1][sr][sc]   = rn0;
      *(int4*)&Ks[cur^1][sr][sc+8] = rn1;
      if (kt < 2) {
        rn0 = *(const int4*)&Kb[(size_t)((kb+kt+2)*64 + sr)*DEP + sc];
        rn1 = *(const int4*)&Kb[(size_t)((kb+kt+2)*64 + sr)*DEP + sc + 8];
      }
      __syncthreads();
    }
  }
  __shared__ float red[4];
  #pragma unroll
  for (int o = 32; o > 0; o >>= 1) mx = fmaxf(mx, __shfl_down(mx, o));
  if (lane == 0) red[w] = mx;
  __syncthreads();
  if (t == 0)
    wsf[P_GMAX + (bh*16 + blockIdx.x)*4 + kz] =
        fmaxf(fmaxf(red[0],red[1]), fmaxf(red[2],red[3]));
}

// ---- K4: fused QK^T -> normalize+table+mask -> exp -> sum/max -> P^T V ----
__global__ __launch_bounds__(256) void k4_fused(
    const float* __restrict__ protok,
    const u16* __restrict__ TG,
    const float* __restrict__ w_att,
    const u16* __restrict__ QPb, const u16* __restrict__ KHb,
    const u16* __restrict__ VTb,
    u16* __restrict__ Ob0, u16* __restrict__ Ob1,
    float* __restrict__ wsf) {
  const int k0 = blockIdx.x*64;
  const int bh = blockIdx.y, b = bh>>3, h = bh&7;
  const int qbase = blockIdx.z * 512;
  u16* Obz = blockIdx.z ? Ob1 : Ob0;
  const u16* tgp = TG + (size_t)(b*2 + ((h < 4) ? 0 : 1))*LL*LL;
  const float gmax = wsf[S_GMAX];
  const float inv_g = w_att[0] / gmax;

  __shared__ u16 Ks[64][72];
  __shared__ u16 Qs[64][72];
  __shared__ u16 Vt[64][72];
  __shared__ u16 Pt[64][72];
  const int t = threadIdx.x;
  const int w = t>>6, lane = t&63, i = lane&15, g2 = lane>>4;
  const int sr = t>>2, sc = (t&3)*16;
  const int qlb = 16*w + g2*4;     // tile-local q base row this lane owns

  {
    size_t sk = ((size_t)bh*LL + k0 + sr)*DEP + sc;
    *(int4*)&Ks[sr][sc]   = *(const int4*)&KHb[sk];
    *(int4*)&Ks[sr][sc+8] = *(const int4*)&KHb[sk+8];
  }
  // prologue prefetch for q0 = qbase
  int4 rq0 = *(const int4*)&QPb[((size_t)bh*LL + qbase + sr)*DEP + sc];
  int4 rq1 = *(const int4*)&QPb[((size_t)bh*LL + qbase + sr)*DEP + sc + 8];
  int4 rv0 = *(const int4*)&VTb[((size_t)bh*DEP + sr)*LL + qbase + sc];
  int4 rv1 = *(const int4*)&VTb[((size_t)bh*DEP + sr)*LL + qbase + sc + 8];
  uint2 tq[4];
  #pragma unroll
  for (int ct=0;ct<4;++ct)
    tq[ct] = *(const uint2*)&tgp[(size_t)(k0 + ct*16 + i)*LL + qbase + qlb];
  __syncthreads();
  bf16x8 kb0[4], kb1[4];
  #pragma unroll
  for (int ct=0;ct<4;++ct) {
    kb0[ct] = *(const bf16x8*)&Ks[ct*16 + i][g2*8];
    kb1[ct] = *(const bf16x8*)&Ks[ct*16 + i][32 + g2*8];
  }
  f32x4 accO[4];
  #pragma unroll
  for (int dt=0;dt<4;++dt) accO[dt] = (f32x4){0.f,0.f,0.f,0.f};
  float lsum = 0.0f, lmax = -INFINITY;

  for (int q0 = qbase; q0 < qbase + 512; q0 += 64) {
    const bool more = (q0 + 64) < (qbase + 512);
    __syncthreads();
    *(int4*)&Qs[sr][sc]   = rq0;
    *(int4*)&Qs[sr][sc+8] = rq1;
    *(int4*)&Vt[sr][sc]   = rv0;
    *(int4*)&Vt[sr][sc+8] = rv1;
    __syncthreads();
    if (more) {
      rq0 = *(const int4*)&QPb[((size_t)bh*LL + q0 + 64 + sr)*DEP + sc];
      rq1 = *(const int4*)&QPb[((size_t)bh*LL + q0 + 64 + sr)*DEP + sc + 8];
      rv0 = *(const int4*)&VTb[((size_t)bh*DEP + sr)*LL + q0 + 64 + sc];
      rv1 = *(const int4*)&VTb[((size_t)bh*DEP + sr)*LL + q0 + 64 + sc + 8];
    }
    // S = Q K^T
    bf16x8 a0 = *(const bf16x8*)&Qs[16*w + i][g2*8];
    bf16x8 a1 = *(const bf16x8*)&Qs[16*w + i][32 + g2*8];
    f32x4 s4[4];
    #pragma unroll
    for (int ct=0; ct<4; ++ct) {
      f32x4 z = (f32x4){0.f,0.f,0.f,0.f};
      z = __builtin_amdgcn_mfma_f32_16x16x32_bf16(a0, kb0[ct], z, 0,0,0);
      z = __builtin_amdgcn_mfma_f32_16x16x32_bf16(a1, kb1[ct], z, 0,0,0);
      s4[ct] = z;
    }
    // next-iteration table prefetch
    uint2 tq2[4];
    if (more) {
      #pragma unroll
      for (int ct=0;ct<4;++ct)
        tq2[ct] = *(const uint2*)&tgp[(size_t)(k0 + ct*16 + i)*LL + q0 + 64 + qlb];
    }
    // normalize + table + mask -> p = exp(s'); write P^T tile (8B stores)
    float madd[4];
    #pragma unroll
    for (int r=0;r<4;++r)
      madd[r] = (protok[b*LL + q0 + qlb + r] == 0.0f) ? NEGV : 0.0f;
    #pragma unroll
    for (int ct=0;ct<4;++ct) {
      float tvv[4];
      tvv[0] = b2f((u16)(tq[ct].x & 0xffffu));
      tvv[1] = b2f((u16)(tq[ct].x >> 16));
      tvv[2] = b2f((u16)(tq[ct].y & 0xffffu));
      tvv[3] = b2f((u16)(tq[ct].y >> 16));
      float pr[4];
      #pragma unroll
      for (int r=0;r<4;++r) {
        float sp = fmaf(s4[ct][r], inv_g, tvv[r] + madd[r]);
        lmax = fmaxf(lmax, sp);
        float p = __expf(sp);
        lsum += p;
        pr[r] = p;
      }
      u32 pk0 = (u32)f2b(pr[0]) | ((u32)f2b(pr[1])<<16);
      u32 pk1 = (u32)f2b(pr[2]) | ((u32)f2b(pr[3])<<16);
      *(uint2*)&Pt[ct*16 + i][qlb] = make_uint2(pk0, pk1);
    }
    __syncthreads();
    // O[k,d] += P^T V
    bf16x8 pa0 = *(const bf16x8*)&Pt[16*w + i][g2*8];
    bf16x8 pa1 = *(const bf16x8*)&Pt[16*w + i][32 + g2*8];
    #pragma unroll
    for (int dt=0; dt<4; ++dt) {
      bf16x8 v0 = *(const bf16x8*)&Vt[dt*16 + i][g2*8];
      bf16x8 v1 = *(const bf16x8*)&Vt[dt*16 + i][32 + g2*8];
      accO[dt] = __builtin_amdgcn_mfma_f32_16x16x32_bf16(pa0, v0, accO[dt], 0,0,0);
      accO[dt] = __builtin_amdgcn_mfma_f32_16x16x32_bf16(pa1, v1, accO[dt], 0,0,0);
    }
    if (more) {
      #pragma unroll
      for (int ct=0;ct<4;++ct) tq[ct] = tq2[ct];
    }
  }
  // store partial O (bf16)
  #pragma unroll
  for (int dt=0;dt<4;++dt)
    #pragma unroll
    for (int r=0;r<4;++r)
      Obz[((size_t)bh*LL + k0 + qlb + r)*DEP + dt*16 + i] = f2b(accO[dt][r]);
  // block-reduce sum & max -> atomics (32 addresses, 32 contenders each)
  __shared__ float rs[4], rm[4];
  #pragma unroll
  for (int o = 32; o > 0; o >>= 1) {
    lsum += __shfl_down(lsum, o);
    lmax = fmaxf(lmax, __shfl_down(lmax, o));
  }
  if (lane == 0) { rs[w] = lsum; rm[w] = lmax; }
  __syncthreads();
  if (t == 0) {
    atomicAdd(&wsf[S_SUM + bh], rs[0]+rs[1]+rs[2]+rs[3]);
    atomicMaxF(&wsf[S_M + bh], fmaxf(fmaxf(rm[0], rm[1]), fmaxf(rm[2], rm[3])));
  }
}

// ---- k_osum: Ob = Ob0 + Ob1 (bf16) ----
__global__ __launch_bounds__(256) void k_osum(const u16* __restrict__ O0,
                                              const u16* __restrict__ O1,
                                              u16* __restrict__ Od) {
  size_t idx = ((size_t)blockIdx.x*256 + threadIdx.x) * 8;
  uint4 x = *(const uint4*)&O0[idx];
  uint4 y = *(const uint4*)&O1[idx];
  uint4 o;
  u32* xp = (u32*)&x; u32* yp = (u32*)&y; u32* op = (u32*)&o;
  #pragma unroll
  for (int j=0;j<4;++j) {
    float lo = b2f((u16)(xp[j] & 0xffffu)) + b2f((u16)(yp[j] & 0xffffu));
    float hi = b2f((u16)(xp[j] >> 16))     + b2f((u16)(yp[j] >> 16));
    op[j] = (u32)f2b(lo) | ((u32)f2b(hi) << 16);
  }
  *(uint4*)&Od[idx] = o;
}

// ---- K4.5: c_bh = (mul/sum) / max_bh(mul * exp(m)/sum) ----
__global__ void k45_cbh(float* ws) {
  int t = threadIdx.x;
  __shared__ float a_sh[32];
  if (t < 32) {
    int b = t >> 3;
    float s = ws[S_SUM + t], m = ws[S_M + t], mul = ws[S_MUL + b];
    a_sh[t] = mul * __expf(m) / s;
  }
  __syncthreads();
  if (t < 32) {
    float amax = -INFINITY;
    #pragma unroll
    for (int i = 0; i < 32; ++i) amax = fmaxf(amax, a_sh[i]);
    int b = t >> 3;
    float s = ws[S_SUM + t], mul = ws[S_MUL + b];
    ws[S_C + t] = (mul / s) / amax;
  }
}

// ---- K5: output projection via MFMA ----
__global__ __launch_bounds__(256) void k5_out(
    const float* __restrict__ protok,
    const float* __restrict__ bo,
    const u16* __restrict__ WTb, const u16* __restrict__ Ob,
    const float* __restrict__ wsf, float* __restrict__ out) {
  const int m0 = blockIdx.x*64, n0 = blockIdx.y*64;
  const int b = m0 >> 10, l0 = m0 & 1023;
  __shared__ u16 As[64][72];
  __shared__ u16 Bs[64][72];
  const int t = threadIdx.x;
  const int w = t>>6, lane = t&63, i = lane&15, g2 = lane>>4;
  const int sr = t>>2, sc = (t&3)*16;
  f32x4 acc[4];
  #pragma unroll
  for (int ct=0;ct<4;++ct) acc[ct] = (f32x4){0.f,0.f,0.f,0.f};

  for (int kk0 = 0; kk0 < DD; kk0 += 64) {
    const int h = kk0 >> 6;
    const float cs = wsf[S_C + b*HH + h];
    __syncthreads();
    {
      union { int4 v[2]; u16 u[16]; } uu;
      size_t so = ((size_t)(b*HH + h)*LL + l0 + sr)*DEP + sc;
      uu.v[0] = *(const int4*)&Ob[so];
      uu.v[1] = *(const int4*)&Ob[so+8];
      u32 pk_[8];
      #pragma unroll
      for (int j=0;j<8;++j)
        pk_[j] = (u32)f2b(b2f(uu.u[2*j])*cs) | ((u32)f2b(b2f(uu.u[2*j+1])*cs)<<16);
      *(int4*)&As[sr][sc]   = make_int4(pk_[0],pk_[1],pk_[2],pk_[3]);
      *(int4*)&As[sr][sc+8] = make_int4(pk_[4],pk_[5],pk_[6],pk_[7]);
    }
    {
      size_t src = ((size_t)(3*DD + n0 + sr))*DD + kk0 + sc;
      *(int4*)&Bs[sr][sc]   = *(const int4*)&WTb[src];
      *(int4*)&Bs[sr][sc+8] = *(const int4*)&WTb[src+8];
    }
    __syncthreads();
    bf16x8 a0 = *(const bf16x8*)&As[16*w + i][g2*8];
    bf16x8 a1 = *(const bf16x8*)&As[16*w + i][32 + g2*8];
    #pragma unroll
    for (int ct=0; ct<4; ++ct) {
      bf16x8 b0 = *(const bf16x8*)&Bs[ct*16 + i][g2*8];
      bf16x8 b1 = *(const bf16x8*)&Bs[ct*16 + i][32 + g2*8];
      acc[ct] = __builtin_amdgcn_mfma_f32_16x16x32_bf16(a0, b0, acc[ct], 0,0,0);
      acc[ct] = __builtin_amdgcn_mfma_f32_16x16x32_bf16(a1, b1, acc[ct], 0,0,0);
    }
  }
  #pragma unroll
  for (int ct=0;ct<4;++ct)
    #pragma unroll
    for (int r=0;r<4;++r) {
      int m = m0 + 16*w + g2*4 + r;
      float keep = (protok[m] != 0.0f) ? 1.0f : 0.0f;
      out[(size_t)m*DD + n0 + ct*16 + i] = (acc[ct][r] + bo[n0 + ct*16 + i]) * keep;
    }
}

extern "C" void kernel_launch(void* const* d_in, const int* in_sizes, int n_in,
                              void* d_out, int out_size, void* d_ws, size_t ws_size,
                              hipStream_t stream) {
  const float* q      = (const float*)d_in[0];
  const float* kv     = (const float*)d_in[1];
  const float* protok = (const float*)d_in[2];
  const float* hb     = (const float*)d_in[3];
  const float* pi     = (const float*)d_in[4];
  // d_in[5] cross_mask derived from protok on the fly
  const float* wq = (const float*)d_in[6];
  const float* bq = (const float*)d_in[7];
  const float* wk = (const float*)d_in[8];
  const float* bk = (const float*)d_in[9];
  const float* wv = (const float*)d_in[10];
  const float* bv = (const float*)d_in[11];
  const float* wo = (const float*)d_in[12];
  const float* bo = (const float*)d_in[13];
  const float* w_att = (const float*)d_in[14];
  const float* w_aug = (const float*)d_in[15];
  float* wsf = (float*)d_ws;
  float* out = (float*)d_out;

  u16* base = (u16*)(wsf + SCAL_F);
  u16* QPb = base;                 // [B,H,L,DEP] bf16; reused as final O after k4
  u16* KHb = QPb + PER_T;          // [B,H,L,DEP] bf16
  u16* VTb = KHb + PER_T;          // [B,H,DEP,L] bf16 (transposed)
  u16* XO  = VTb + PER_T;          // 2*PER_T: Xb (k_xb..k1), then Ob0/Ob1 (k4..)
  u16* WTb = XO  + 2*PER_T;        // [4][512][512] bf16 (transposed weights)
  u16* TG  = WTb + 4*DD*DD;        // [8][1024][1024] bf16 (scaled transposed tables)
  u16* Xb  = XO;
  u16* Ob0 = XO;
  u16* Ob1 = XO + PER_T;
  u16* Obf = QPb;                  // final O overwrites QPb (dead after k4)

  k0_init   <<<1, 64, 0, stream>>>(wsf);
  k_count   <<<4, 256, 0, stream>>>(protok, wsf);
  k_tminmax <<<256, 256, 0, stream>>>(hb, pi, wsf);
  k_red1    <<<1, 256, 0, stream>>>(wsf);
  k_taug    <<<dim3(16, 16, 8), 256, 0, stream>>>(hb, pi, w_aug, wsf, TG);
  k_xb      <<<2048, 256, 0, stream>>>(q, kv, Xb);
  k_wt      <<<dim3(8, 8, 4), 256, 0, stream>>>(wq, wk, wv, wo, WTb);
  k1_proj   <<<dim3(64, 8, 3), 256, 0, stream>>>(protok, bq, bk, bv, Xb, WTb, QPb, KHb, VTb);
  k3_gmax   <<<dim3(16, 32, 4), 256, 0, stream>>>(QPb, KHb, wsf);
  k_red2    <<<1, 256, 0, stream>>>(wsf);
  k4_fused  <<<dim3(16, 32, 2), 256, 0, stream>>>(protok, TG, w_att,
                                                  QPb, KHb, VTb, Ob0, Ob1, wsf);
  k_osum    <<<1024, 256, 0, stream>>>(Ob0, Ob1, Obf);
  k45_cbh   <<<1, 64, 0, stream>>>(wsf);
  k5_out    <<<dim3(64, 8), 256, 0, stream>>>(protok, bo, WTb, Obf, wsf, out);
}

// Round 6
// 215.305 us; speedup vs baseline: 1.1651x; 1.1651x over previous
//
#include <hip/hip_runtime.h>
#include <math.h>

#define BB 4
#define LL 1024
#define DD 512
#define HH 8
#define DEP 64
#define NEGV (-1.0e9f)

typedef __attribute__((ext_vector_type(8))) short bf16x8;
typedef __attribute__((ext_vector_type(4))) float f32x4;
typedef unsigned short u16;
typedef unsigned int u32;

// ---- scalar slots in ws (float offsets) ----
#define S_TMAX 1
#define S_TMIN 2
#define S_MUL  4     // 4
#define S_SUM  8     // 32
#define S_M    40    // 32
#define P_TMAX 128   // 256 partials (k_tminmax)
#define P_TMIN 384   // 256 partials
#define P_GMAX 640   // 1024 partials (k3: 8 qstripes x 32 bh x 4 kz)
#define SCAL_F 1792
#define PER_T  (BB*HH*LL*DEP)   // 2097152 bf16 elems per tensor

__device__ inline u16 f2b(float x) {
  u32 u = __float_as_uint(x);
  return (u16)((u + 0x7FFFu + ((u >> 16) & 1u)) >> 16);
}
__device__ inline float b2f(u16 h) { return __uint_as_float(((u32)h) << 16); }

__device__ inline void atomicMaxF(float* addr, float val) {
  unsigned int* ua = (unsigned int*)addr;
  unsigned int old = *ua;
  while (__uint_as_float(old) < val) {
    unsigned int assumed = old;
    old = atomicCAS(ua, assumed, __float_as_uint(val));
    if (old == assumed) break;
  }
}

// ---- k_tminmax: table min/max partials + (blocks 0-3) protok count + (block 4) init ----
__global__ __launch_bounds__(256) void k_tminmax(const float* __restrict__ hb,
                                                 const float* __restrict__ pi,
                                                 const float* __restrict__ protok,
                                                 float* __restrict__ ws) {
  const int t = threadIdx.x;
  // fold-in: init accumulator scalars (block 4)
  if (blockIdx.x == 4 && t < 32) {
    ws[S_SUM + t] = 0.0f; ws[S_M + t] = -INFINITY;
  }
  // fold-in: count_nonzero(protok) (blocks 0-3)
  if (blockIdx.x < 4) {
    int b = blockIdx.x;
    int cnt = 0;
    for (int l = t; l < LL; l += 256)
      cnt += (protok[b*LL + l] != 0.0f) ? 1 : 0;
    __shared__ int shc[4];
    int lane = t & 63, w = t >> 6;
    #pragma unroll
    for (int o = 32; o > 0; o >>= 1) cnt += __shfl_down(cnt, o);
    if (lane == 0) shc[w] = cnt;
    __syncthreads();
    if (t == 0) ws[S_MUL + b] = (float)(shc[0] + shc[1] + shc[2] + shc[3]);
  }
  // main duty: scan tables
  const int g = blockIdx.x*256 + t;    // 65536 threads
  float mx = -INFINITY, mn = INFINITY;
  #pragma unroll
  for (int rep = 0; rep < 4; ++rep) {
    float4 a[4], c[4];
    #pragma unroll
    for (int j = 0; j < 4; ++j) {
      size_t idx = (size_t)rep*262144 + (size_t)j*65536 + g;
      a[j] = ((const float4*)hb)[idx];
      c[j] = ((const float4*)pi)[idx];
    }
    #pragma unroll
    for (int j = 0; j < 4; ++j) {
      mx = fmaxf(mx, fmaxf(fmaxf(a[j].x, a[j].y), fmaxf(a[j].z, a[j].w)));
      mx = fmaxf(mx, fmaxf(fmaxf(c[j].x, c[j].y), fmaxf(c[j].z, c[j].w)));
      mn = fminf(mn, fminf(fminf(a[j].x, a[j].y), fminf(a[j].z, a[j].w)));
      mn = fminf(mn, fminf(fminf(c[j].x, c[j].y), fminf(c[j].z, c[j].w)));
    }
  }
  __shared__ float shx[4], shn[4];
  int lane = t & 63, w = t >> 6;
  #pragma unroll
  for (int o = 32; o > 0; o >>= 1) {
    mx = fmaxf(mx, __shfl_down(mx, o));
    mn = fminf(mn, __shfl_down(mn, o));
  }
  if (lane == 0) { shx[w] = mx; shn[w] = mn; }
  __syncthreads();
  if (t == 0) {
    ws[P_TMAX + blockIdx.x] = fmaxf(fmaxf(shx[0], shx[1]), fmaxf(shx[2], shx[3]));
    ws[P_TMIN + blockIdx.x] = fminf(fminf(shn[0], shn[1]), fminf(shn[2], shn[3]));
  }
}

// ---- k_prep: [0,2048) xb-convert | [2048,2304) weight transpose | 2304 red1 ----
__global__ __launch_bounds__(256) void k_prep(
    const float* __restrict__ q, const float* __restrict__ kv,
    const float* __restrict__ wq, const float* __restrict__ wk,
    const float* __restrict__ wv, const float* __restrict__ wo,
    u16* __restrict__ Xb, u16* __restrict__ WTb, float* __restrict__ ws) {
  const int bid = blockIdx.x;
  const int t = threadIdx.x;
  if (bid < 2048) {                    // ---- xb duty
    int tg = bid*256 + t;
    int which = tg >> 18;
    size_t off8 = (size_t)(tg & 262143) * 8;
    const float* s = which ? kv : q;
    float4 f0 = *(const float4*)&s[off8];
    float4 f1 = *(const float4*)&s[off8 + 4];
    u32 p0 = (u32)f2b(f0.x) | ((u32)f2b(f0.y) << 16);
    u32 p1 = (u32)f2b(f0.z) | ((u32)f2b(f0.w) << 16);
    u32 p2 = (u32)f2b(f1.x) | ((u32)f2b(f1.y) << 16);
    u32 p3 = (u32)f2b(f1.z) | ((u32)f2b(f1.w) << 16);
    *(int4*)&Xb[(size_t)which*PER_T + off8] = make_int4(p0, p1, p2, p3);
  } else if (bid < 2304) {             // ---- weight transpose duty
    const int wid = bid - 2048;
    const int g = wid >> 6, rem = wid & 63;
    const int k0 = (rem >> 3)*64, n0 = (rem & 7)*64;
    const float* W = (g==0)?wq:(g==1)?wk:(g==2)?wv:wo;
    __shared__ u16 Ls[64][72];
    {
      const int r = t>>2, c16 = (t&3)*16;
      float v[16];
      #pragma unroll
      for (int j=0;j<4;++j) {
        float4 f = *(const float4*)&W[(size_t)(k0+r)*DD + n0 + c16 + 4*j];
        v[4*j]=f.x; v[4*j+1]=f.y; v[4*j+2]=f.z; v[4*j+3]=f.w;
      }
      u32 pk_[8];
      #pragma unroll
      for (int j=0;j<8;++j) pk_[j] = (u32)f2b(v[2*j]) | ((u32)f2b(v[2*j+1])<<16);
      *(int4*)&Ls[r][c16]   = make_int4(pk_[0],pk_[1],pk_[2],pk_[3]);
      *(int4*)&Ls[r][c16+8] = make_int4(pk_[4],pk_[5],pk_[6],pk_[7]);
    }
    __syncthreads();
    {
      const int n = t>>2, kk = (t&3)*16;
      u16 u[16];
      #pragma unroll
      for (int j=0;j<16;++j) u[j] = Ls[kk+j][n];
      u32 q_[8];
      #pragma unroll
      for (int j=0;j<8;++j) q_[j] = (u32)u[2*j] | ((u32)u[2*j+1]<<16);
      size_t dst = ((size_t)(g*DD + n0 + n))*DD + k0 + kk;
      *(int4*)&WTb[dst]   = make_int4(q_[0],q_[1],q_[2],q_[3]);
      *(int4*)&WTb[dst+8] = make_int4(q_[4],q_[5],q_[6],q_[7]);
    }
  } else {                             // ---- red1 duty (single block)
    float tm = ws[P_TMAX + t];
    float tn = ws[P_TMIN + t];
    __shared__ float st[4], sn[4];
    int lane = t & 63, w = t >> 6;
    #pragma unroll
    for (int o = 32; o > 0; o >>= 1) {
      tm = fmaxf(tm, __shfl_down(tm, o));
      tn = fminf(tn, __shfl_down(tn, o));
    }
    if (lane == 0) { st[w] = tm; sn[w] = tn; }
    __syncthreads();
    if (t == 0) {
      ws[S_TMAX] = fmaxf(fmaxf(st[0], st[1]), fmaxf(st[2], st[3]));
      ws[S_TMIN] = fminf(fminf(sn[0], sn[1]), fminf(sn[2], sn[3]));
    }
  }
}

// ---- K1: three input projections via MFMA; V is stored transposed ----
__global__ __launch_bounds__(256) void k1_proj(
    const float* __restrict__ protok,
    const float* __restrict__ bq, const float* __restrict__ bk,
    const float* __restrict__ bv,
    const u16* __restrict__ Xb, const u16* __restrict__ WTb,
    u16* __restrict__ QPb, u16* __restrict__ KHb, u16* __restrict__ VTb) {
  const int gid = blockIdx.z;
  const u16* X = Xb + (gid == 0 ? 0 : (size_t)PER_T);
  const float* bia = (gid == 0) ? bq : (gid == 1) ? bk : bv;
  const int m0 = blockIdx.x*64;
  const int h  = blockIdx.y;
  __shared__ u16 As[64][72];
  __shared__ u16 Bs[64][72];
  const int t = threadIdx.x;
  const int w = t>>6, lane = t&63, i = lane&15, g2 = lane>>4;
  const int sr = t>>2, sc = (t&3)*16;

  f32x4 acc[4];
  #pragma unroll
  for (int ct=0;ct<4;++ct) acc[ct] = (f32x4){0.f,0.f,0.f,0.f};

  for (int kk0 = 0; kk0 < DD; kk0 += 64) {
    __syncthreads();
    {
      size_t sx = (size_t)(m0+sr)*DD + kk0 + sc;
      *(int4*)&As[sr][sc]   = *(const int4*)&X[sx];
      *(int4*)&As[sr][sc+8] = *(const int4*)&X[sx+8];
    }
    {
      size_t src = ((size_t)(gid*DD + h*64 + sr))*DD + kk0 + sc;
      *(int4*)&Bs[sr][sc]   = *(const int4*)&WTb[src];
      *(int4*)&Bs[sr][sc+8] = *(const int4*)&WTb[src+8];
    }
    __syncthreads();
    bf16x8 a0 = *(const bf16x8*)&As[16*w + i][g2*8];
    bf16x8 a1 = *(const bf16x8*)&As[16*w + i][32 + g2*8];
    #pragma unroll
    for (int ct=0; ct<4; ++ct) {
      bf16x8 b0 = *(const bf16x8*)&Bs[ct*16 + i][g2*8];
      bf16x8 b1 = *(const bf16x8*)&Bs[ct*16 + i][32 + g2*8];
      acc[ct] = __builtin_amdgcn_mfma_f32_16x16x32_bf16(a0, b0, acc[ct], 0,0,0);
      acc[ct] = __builtin_amdgcn_mfma_f32_16x16x32_bf16(a1, b1, acc[ct], 0,0,0);
    }
  }
  __syncthreads();
  const int lrow = 16*w + g2*4;
  if (gid == 2) {
    #pragma unroll
    for (int ct=0;ct<4;++ct)
      #pragma unroll
      for (int r=0;r<4;++r)
        As[lrow + r][ct*16 + i] = f2b(acc[ct][r] + bia[h*64 + ct*16 + i]);
    __syncthreads();
    const int b = m0 >> 10, l0 = m0 & 1023;
    const int d = t>>2, lc = (t&3)*16;
    u16 u[16];
    #pragma unroll
    for (int j=0;j<16;++j) u[j] = As[lc+j][d];
    u32 q_[8];
    #pragma unroll
    for (int j=0;j<8;++j) q_[j] = (u32)u[2*j] | ((u32)u[2*j+1]<<16);
    size_t dst = ((size_t)(b*HH + h)*DEP + d)*LL + l0 + lc;
    *(int4*)&VTb[dst]   = make_int4(q_[0],q_[1],q_[2],q_[3]);
    *(int4*)&VTb[dst+8] = make_int4(q_[4],q_[5],q_[6],q_[7]);
  } else {
    u16* Y = (gid == 0) ? QPb : KHb;
    #pragma unroll
    for (int ct=0;ct<4;++ct)
      #pragma unroll
      for (int r=0;r<4;++r) {
        int m = m0 + lrow + r;
        float keep = (gid == 0) ? ((protok[m] != 0.0f) ? 1.0f : 0.0f) : 1.0f;
        int b = m >> 10, l = m & 1023;
        float val = (acc[ct][r] + bia[h*64 + ct*16 + i]) * keep;
        Y[((size_t)(b*HH + h)*LL + l)*DEP + ct*16 + i] = f2b(val);
      }
  }
}

// ---- K3: partial max of raw QK^T; 128 q-rows x 4 K-tiles per block ----
__global__ __launch_bounds__(256) void k3_gmax(
    const u16* __restrict__ QPb, const u16* __restrict__ KHb,
    float* __restrict__ wsf) {
  const int q0 = blockIdx.x*128, bh = blockIdx.y, kz = blockIdx.z;
  __shared__ u16 Qs[2][64][72];
  __shared__ u16 Ks[2][64][72];
  const int t = threadIdx.x;
  const int w = t>>6, lane = t&63, i = lane&15, g2 = lane>>4;
  const int sr = t>>2, sc = (t&3)*16;
  const u16* Qb = QPb + (size_t)bh*LL*DEP;
  const u16* Kb = KHb + (size_t)bh*LL*DEP;
  #pragma unroll
  for (int qs = 0; qs < 2; ++qs) {
    size_t sq = (size_t)(q0 + qs*64 + sr)*DEP + sc;
    *(int4*)&Qs[qs][sr][sc]   = *(const int4*)&Qb[sq];
    *(int4*)&Qs[qs][sr][sc+8] = *(const int4*)&Qb[sq+8];
  }
  const int kb = kz*4;
  int4 rn0 = *(const int4*)&Kb[(size_t)(kb*64 + sr)*DEP + sc];
  int4 rn1 = *(const int4*)&Kb[(size_t)(kb*64 + sr)*DEP + sc + 8];
  __syncthreads();
  *(int4*)&Ks[0][sr][sc]   = rn0;
  *(int4*)&Ks[0][sr][sc+8] = rn1;
  rn0 = *(const int4*)&Kb[(size_t)((kb+1)*64 + sr)*DEP + sc];
  rn1 = *(const int4*)&Kb[(size_t)((kb+1)*64 + sr)*DEP + sc + 8];
  __syncthreads();
  bf16x8 a0[2], a1[2];
  #pragma unroll
  for (int qs = 0; qs < 2; ++qs) {
    a0[qs] = *(const bf16x8*)&Qs[qs][16*w + i][g2*8];
    a1[qs] = *(const bf16x8*)&Qs[qs][16*w + i][32 + g2*8];
  }
  float mx = -INFINITY;
  for (int kt = 0; kt < 4; ++kt) {
    const int cur = kt & 1;
    #pragma unroll
    for (int ct=0;ct<4;++ct) {
      bf16x8 b0 = *(const bf16x8*)&Ks[cur][ct*16 + i][g2*8];
      bf16x8 b1 = *(const bf16x8*)&Ks[cur][ct*16 + i][32 + g2*8];
      #pragma unroll
      for (int qs=0;qs<2;++qs) {
        f32x4 z = (f32x4){0.f,0.f,0.f,0.f};
        z = __builtin_amdgcn_mfma_f32_16x16x32_bf16(a0[qs], b0, z, 0,0,0);
        z = __builtin_amdgcn_mfma_f32_16x16x32_bf16(a1[qs], b1, z, 0,0,0);
        mx = fmaxf(mx, fmaxf(fmaxf(z[0],z[1]), fmaxf(z[2],z[3])));
      }
    }
    if (kt < 3) {
      __syncthreads();
      *(int4*)&Ks[cur^1][sr][sc]   = rn0;
      *(int4*)&Ks[cur^1][sr][sc+8] = rn1;
      if (kt < 2) {
        rn0 = *(const int4*)&Kb[(size_t)((kb+kt+2)*64 + sr)*DEP + sc];
        rn1 = *(const int4*)&Kb[(size_t)((kb+kt+2)*64 + sr)*DEP + sc + 8];
      }
      __syncthreads();
    }
  }
  __shared__ float red[4];
  #pragma unroll
  for (int o = 32; o > 0; o >>= 1) mx = fmaxf(mx, __shfl_down(mx, o));
  if (lane == 0) red[w] = mx;
  __syncthreads();
  if (t == 0)
    wsf[P_GMAX + (bh*8 + blockIdx.x)*4 + kz] =
        fmaxf(fmaxf(red[0],red[1]), fmaxf(red[2],red[3]));
}

// ---- K4: fused QK^T -> normalize+table+mask -> exp -> sum/max -> P^T V ----
__global__ __launch_bounds__(256) void k4_fused(
    const float* __restrict__ protok,
    const float* __restrict__ hb, const float* __restrict__ pi,
    const float* __restrict__ w_att, const float* __restrict__ w_aug,
    const u16* __restrict__ QPb, const u16* __restrict__ KHb,
    const u16* __restrict__ VTb,
    u16* __restrict__ Ob0, u16* __restrict__ Ob1,
    float* __restrict__ wsf) {
  const int k0 = blockIdx.x*64;
  const int bh = blockIdx.y, b = bh>>3, h = bh&7;
  const int qbase = blockIdx.z * 512;
  u16* Obz = blockIdx.z ? Ob1 : Ob0;
  const float* tab = ((h < 4) ? hb : pi) + (size_t)b*LL*LL;
  const int t = threadIdx.x;
  const int w = t>>6, lane = t&63, i = lane&15, g2 = lane>>4;
  const int sr = t>>2, sc = (t&3)*16;
  const int qlb = 16*w + g2*4;

  // inline red2: fold the 1024 gmax partials (L2-hot)
  __shared__ float gsh;
  {
    float gm = -INFINITY;
    #pragma unroll
    for (int j=0;j<4;++j) gm = fmaxf(gm, wsf[P_GMAX + j*256 + t]);
    __shared__ float red[4];
    #pragma unroll
    for (int o = 32; o > 0; o >>= 1) gm = fmaxf(gm, __shfl_down(gm, o));
    if (lane == 0) red[w] = gm;
    __syncthreads();
    if (t == 0) gsh = fmaxf(fmaxf(red[0],red[1]), fmaxf(red[2],red[3]));
  }
  const float tmaxr = wsf[S_TMAX], tminr = wsf[S_TMIN];
  const float wa = w_att[0], wg = w_aug[0];
  const float tden = (wg >= 0.0f) ? (wg * tmaxr) : (wg * tminr);
  const float inv_t = wg / tden;

  __shared__ u16 Ks[64][72];
  __shared__ u16 Qs[64][72];
  __shared__ u16 Vt[64][72];
  __shared__ u16 Pt[64][72];
  {
    size_t sk = ((size_t)bh*LL + k0 + sr)*DEP + sc;
    *(int4*)&Ks[sr][sc]   = *(const int4*)&KHb[sk];
    *(int4*)&Ks[sr][sc+8] = *(const int4*)&KHb[sk+8];
  }
  // prologue prefetch for q0 = qbase
  int4 rq0 = *(const int4*)&QPb[((size_t)bh*LL + qbase + sr)*DEP + sc];
  int4 rq1 = *(const int4*)&QPb[((size_t)bh*LL + qbase + sr)*DEP + sc + 8];
  int4 rv0 = *(const int4*)&VTb[((size_t)bh*DEP + sr)*LL + qbase + sc];
  int4 rv1 = *(const int4*)&VTb[((size_t)bh*DEP + sr)*LL + qbase + sc + 8];
  float tvr[4][4];
  #pragma unroll
  for (int r=0;r<4;++r)
    #pragma unroll
    for (int ct=0;ct<4;++ct)
      tvr[r][ct] = tab[(size_t)(qbase + qlb + r)*LL + k0 + ct*16 + i];
  __syncthreads();
  const float inv_g = wa / gsh;
  bf16x8 kb0[4], kb1[4];
  #pragma unroll
  for (int ct=0;ct<4;++ct) {
    kb0[ct] = *(const bf16x8*)&Ks[ct*16 + i][g2*8];
    kb1[ct] = *(const bf16x8*)&Ks[ct*16 + i][32 + g2*8];
  }
  f32x4 accO[4];
  #pragma unroll
  for (int dt=0;dt<4;++dt) accO[dt] = (f32x4){0.f,0.f,0.f,0.f};
  float lsum = 0.0f, lmax = -INFINITY;

  for (int q0 = qbase; q0 < qbase + 512; q0 += 64) {
    const bool more = (q0 + 64) < (qbase + 512);
    __syncthreads();
    *(int4*)&Qs[sr][sc]   = rq0;
    *(int4*)&Qs[sr][sc+8] = rq1;
    *(int4*)&Vt[sr][sc]   = rv0;
    *(int4*)&Vt[sr][sc+8] = rv1;
    __syncthreads();
    if (more) {
      rq0 = *(const int4*)&QPb[((size_t)bh*LL + q0 + 64 + sr)*DEP + sc];
      rq1 = *(const int4*)&QPb[((size_t)bh*LL + q0 + 64 + sr)*DEP + sc + 8];
      rv0 = *(const int4*)&VTb[((size_t)bh*DEP + sr)*LL + q0 + 64 + sc];
      rv1 = *(const int4*)&VTb[((size_t)bh*DEP + sr)*LL + q0 + 64 + sc + 8];
    }
    // S = Q K^T
    bf16x8 a0 = *(const bf16x8*)&Qs[16*w + i][g2*8];
    bf16x8 a1 = *(const bf16x8*)&Qs[16*w + i][32 + g2*8];
    f32x4 s4[4];
    #pragma unroll
    for (int ct=0; ct<4; ++ct) {
      f32x4 z = (f32x4){0.f,0.f,0.f,0.f};
      z = __builtin_amdgcn_mfma_f32_16x16x32_bf16(a0, kb0[ct], z, 0,0,0);
      z = __builtin_amdgcn_mfma_f32_16x16x32_bf16(a1, kb1[ct], z, 0,0,0);
      s4[ct] = z;
    }
    // next-iteration table prefetch (row-contiguous f32 reads; L3 absorbs)
    float tv2[4][4];
    if (more) {
      #pragma unroll
      for (int r=0;r<4;++r)
        #pragma unroll
        for (int ct=0;ct<4;++ct)
          tv2[r][ct] = tab[(size_t)(q0 + 64 + qlb + r)*LL + k0 + ct*16 + i];
    }
    // normalize + table + mask -> p = exp(s'); write P^T tile (8B stores)
    float madd[4];
    #pragma unroll
    for (int r=0;r<4;++r)
      madd[r] = (protok[b*LL + q0 + qlb + r] == 0.0f) ? NEGV : 0.0f;
    #pragma unroll
    for (int ct=0;ct<4;++ct) {
      float pr[4];
      #pragma unroll
      for (int r=0;r<4;++r) {
        float sp = fmaf(s4[ct][r], inv_g, fmaf(tvr[r][ct], inv_t, madd[r]));
        lmax = fmaxf(lmax, sp);
        float p = __expf(sp);
        lsum += p;
        pr[r] = p;
      }
      u32 pk0 = (u32)f2b(pr[0]) | ((u32)f2b(pr[1])<<16);
      u32 pk1 = (u32)f2b(pr[2]) | ((u32)f2b(pr[3])<<16);
      *(uint2*)&Pt[ct*16 + i][qlb] = make_uint2(pk0, pk1);
    }
    __syncthreads();
    // O[k,d] += P^T V
    bf16x8 pa0 = *(const bf16x8*)&Pt[16*w + i][g2*8];
    bf16x8 pa1 = *(const bf16x8*)&Pt[16*w + i][32 + g2*8];
    #pragma unroll
    for (int dt=0; dt<4; ++dt) {
      bf16x8 v0 = *(const bf16x8*)&Vt[dt*16 + i][g2*8];
      bf16x8 v1 = *(const bf16x8*)&Vt[dt*16 + i][32 + g2*8];
      accO[dt] = __builtin_amdgcn_mfma_f32_16x16x32_bf16(pa0, v0, accO[dt], 0,0,0);
      accO[dt] = __builtin_amdgcn_mfma_f32_16x16x32_bf16(pa1, v1, accO[dt], 0,0,0);
    }
    if (more) {
      #pragma unroll
      for (int r=0;r<4;++r)
        #pragma unroll
        for (int ct=0;ct<4;++ct) tvr[r][ct] = tv2[r][ct];
    }
  }
  // store partial O (bf16)
  #pragma unroll
  for (int dt=0;dt<4;++dt)
    #pragma unroll
    for (int r=0;r<4;++r)
      Obz[((size_t)bh*LL + k0 + qlb + r)*DEP + dt*16 + i] = f2b(accO[dt][r]);
  // block-reduce sum & max -> atomics (32 addresses, 32 contenders each)
  __shared__ float rs[4], rm[4];
  #pragma unroll
  for (int o = 32; o > 0; o >>= 1) {
    lsum += __shfl_down(lsum, o);
    lmax = fmaxf(lmax, __shfl_down(lmax, o));
  }
  if (lane == 0) { rs[w] = lsum; rm[w] = lmax; }
  __syncthreads();
  if (t == 0) {
    atomicAdd(&wsf[S_SUM + bh], rs[0]+rs[1]+rs[2]+rs[3]);
    atomicMaxF(&wsf[S_M + bh], fmaxf(fmaxf(rm[0], rm[1]), fmaxf(rm[2], rm[3])));
  }
}

// ---- K5: output projection via MFMA; inline cbh + O0+O1 sum ----
__global__ __launch_bounds__(256) void k5_out(
    const float* __restrict__ protok,
    const float* __restrict__ bo,
    const u16* __restrict__ WTb,
    const u16* __restrict__ O0, const u16* __restrict__ O1,
    const float* __restrict__ wsf, float* __restrict__ out) {
  const int m0 = blockIdx.x*64, n0 = blockIdx.y*64;
  const int b = m0 >> 10, l0 = m0 & 1023;
  __shared__ u16 As[64][72];
  __shared__ u16 Bs[64][72];
  __shared__ float csh[8];
  const int t = threadIdx.x;
  const int w = t>>6, lane = t&63, i = lane&15, g2 = lane>>4;
  const int sr = t>>2, sc = (t&3)*16;

  // inline k45: c_h = (mul_b/sum_bh) / max_bh'(mul_b' * exp(m)/sum)
  __shared__ float ash[32];
  if (t < 32)
    ash[t] = wsf[S_MUL + (t>>3)] * __expf(wsf[S_M + t]) / wsf[S_SUM + t];
  __syncthreads();
  if (t < 8) {
    float amax = -INFINITY;
    #pragma unroll
    for (int j = 0; j < 32; ++j) amax = fmaxf(amax, ash[j]);
    csh[t] = (wsf[S_MUL + b] / wsf[S_SUM + b*HH + t]) / amax;
  }

  f32x4 acc[4];
  #pragma unroll
  for (int ct=0;ct<4;++ct) acc[ct] = (f32x4){0.f,0.f,0.f,0.f};

  for (int kk0 = 0; kk0 < DD; kk0 += 64) {
    const int h = kk0 >> 6;
    __syncthreads();
    {
      union { int4 v[2]; u16 u[16]; } u0, u1;
      size_t so = ((size_t)(b*HH + h)*LL + l0 + sr)*DEP + sc;
      u0.v[0] = *(const int4*)&O0[so];
      u0.v[1] = *(const int4*)&O0[so+8];
      u1.v[0] = *(const int4*)&O1[so];
      u1.v[1] = *(const int4*)&O1[so+8];
      const float cs = csh[h];
      u32 pk_[8];
      #pragma unroll
      for (int j=0;j<8;++j) {
        float lo = (b2f(u0.u[2*j])   + b2f(u1.u[2*j]))   * cs;
        float hi = (b2f(u0.u[2*j+1]) + b2f(u1.u[2*j+1])) * cs;
        pk_[j] = (u32)f2b(lo) | ((u32)f2b(hi)<<16);
      }
      *(int4*)&As[sr][sc]   = make_int4(pk_[0],pk_[1],pk_[2],pk_[3]);
      *(int4*)&As[sr][sc+8] = make_int4(pk_[4],pk_[5],pk_[6],pk_[7]);
    }
    {
      size_t src = ((size_t)(3*DD + n0 + sr))*DD + kk0 + sc;
      *(int4*)&Bs[sr][sc]   = *(const int4*)&WTb[src];
      *(int4*)&Bs[sr][sc+8] = *(const int4*)&WTb[src+8];
    }
    __syncthreads();
    bf16x8 a0 = *(const bf16x8*)&As[16*w + i][g2*8];
    bf16x8 a1 = *(const bf16x8*)&As[16*w + i][32 + g2*8];
    #pragma unroll
    for (int ct=0; ct<4; ++ct) {
      bf16x8 b0 = *(const bf16x8*)&Bs[ct*16 + i][g2*8];
      bf16x8 b1 = *(const bf16x8*)&Bs[ct*16 + i][32 + g2*8];
      acc[ct] = __builtin_amdgcn_mfma_f32_16x16x32_bf16(a0, b0, acc[ct], 0,0,0);
      acc[ct] = __builtin_amdgcn_mfma_f32_16x16x32_bf16(a1, b1, acc[ct], 0,0,0);
    }
  }
  #pragma unroll
  for (int ct=0;ct<4;++ct)
    #pragma unroll
    for (int r=0;r<4;++r) {
      int m = m0 + 16*w + g2*4 + r;
      float keep = (protok[m] != 0.0f) ? 1.0f : 0.0f;
      out[(size_t)m*DD + n0 + ct*16 + i] = (acc[ct][r] + bo[n0 + ct*16 + i]) * keep;
    }
}

extern "C" void kernel_launch(void* const* d_in, const int* in_sizes, int n_in,
                              void* d_out, int out_size, void* d_ws, size_t ws_size,
                              hipStream_t stream) {
  const float* q      = (const float*)d_in[0];
  const float* kv     = (const float*)d_in[1];
  const float* protok = (const float*)d_in[2];
  const float* hb     = (const float*)d_in[3];
  const float* pi     = (const float*)d_in[4];
  // d_in[5] cross_mask derived from protok on the fly
  const float* wq = (const float*)d_in[6];
  const float* bq = (const float*)d_in[7];
  const float* wk = (const float*)d_in[8];
  const float* bk = (const float*)d_in[9];
  const float* wv = (const float*)d_in[10];
  const float* bv = (const float*)d_in[11];
  const float* wo = (const float*)d_in[12];
  const float* bo = (const float*)d_in[13];
  const float* w_att = (const float*)d_in[14];
  const float* w_aug = (const float*)d_in[15];
  float* wsf = (float*)d_ws;
  float* out = (float*)d_out;

  u16* base = (u16*)(wsf + SCAL_F);
  u16* QPb = base;                 // [B,H,L,DEP] bf16
  u16* KHb = QPb + PER_T;          // [B,H,L,DEP] bf16
  u16* VTb = KHb + PER_T;          // [B,H,DEP,L] bf16 (transposed)
  u16* XO  = VTb + PER_T;          // 2*PER_T: Xb (prep..k1), then Ob0/Ob1 (k4..)
  u16* WTb = XO  + 2*PER_T;        // [4][512][512] bf16 (transposed weights)
  u16* Xb  = XO;
  u16* Ob0 = XO;
  u16* Ob1 = XO + PER_T;

  k_tminmax <<<256, 256, 0, stream>>>(hb, pi, protok, wsf);
  k_prep    <<<2305, 256, 0, stream>>>(q, kv, wq, wk, wv, wo, Xb, WTb, wsf);
  k1_proj   <<<dim3(64, 8, 3), 256, 0, stream>>>(protok, bq, bk, bv, Xb, WTb, QPb, KHb, VTb);
  k3_gmax   <<<dim3(8, 32, 4), 256, 0, stream>>>(QPb, KHb, wsf);
  k4_fused  <<<dim3(16, 32, 2), 256, 0, stream>>>(protok, hb, pi, w_att, w_aug,
                                                  QPb, KHb, VTb, Ob0, Ob1, wsf);
  k5_out    <<<dim3(64, 8), 256, 0, stream>>>(protok, bo, WTb, Ob0, Ob1, wsf, out);
}